// Round 6
// baseline (2377.214 us; speedup 1.0000x reference)
//
#include <hip/hip_runtime.h>
#include <hip/hip_bf16.h>

// TimeLSTM: B=2048, T=256, IN=65 (1 time-delta + 64 features), H=256, gates=1024.
//
// Round 6: async-DMA streaming. r5 isolated a ~16k cyc/step stall = the 64
// streamed L2 loads serialized at ~250cyc latency (reg double-buffer caps
// in-flight at 8 loads; 1 wave/SIMD => no TLP to hide it). Fix: stream tier
// goes through __builtin_amdgcn_global_load_lds (16B/lane DMA, vmcnt-tracked,
// depth limited by vmcnt not registers) into wave-private LDS transit
// double-buffers; consume with ds_read_b128 + manual s_waitcnt vmcnt(N).
// Wave-private buffers => no __syncthreads => no vmcnt(0) drain (m97 lesson).
//
// W tiers per wave (160 frags x 1KB):
//   kt 0..3 -> 64 frags in AGPRs (asm "a" B-operand; r5-verified, no remat)
//   kt 4    -> 16 frags/wave LDS-resident (64KB block)
//   kt 5..9 -> 80 frags/wave streamed: 10 batches x 8 DMA frags, 2 transit
//              bufs x 8KB per wave (64KB block), refill batch s+2 at s.
// LDS: 64K resident | 64K transit | A 11008 | td 64 | out 64 = 142208.
// Manual waitcnt (gfx9 imm: vmcnt[3:0]|exp[6:4]|lgkm[11:8], lgkm=15,exp=7
// = no wait): consume batch s waits vmcnt<= younger-loads count (in-order
// retirement, m135): s=0,1 -> 10 (next batch 8 + px 2), s=2..8 -> 8, s=9 -> 0.
// DMA->ds_read buffer-reuse hazard handled by program order (ds_reads + MFMA
// consume before refilling that buffer; LDS pipe is FIFO vs later DMA landing).
// C/D layout (m89): col = lane&15, row = (lane>>4)*4 + reg. Wave w owns cols
// w*64 + jt*16 + l15; all 4 gates of a column in one lane -> lane-local epilogue.

typedef __bf16 v8bf __attribute__((ext_vector_type(8)));
typedef __bf16 v4bf __attribute__((ext_vector_type(4)));
typedef float f32x4 __attribute__((ext_vector_type(4)));
typedef int   v4i  __attribute__((ext_vector_type(4)));

#define B_SZ 2048
#define T_SZ 256
#define IN_SZ 65
#define NKT 10          // 320 / 32 k-steps
#define MBLK 16
#define NBLOCKS (B_SZ / MBLK)   // 128
#define THREADS 256
#define NW 4

#define WREG_KT 4                              // kt 0..3 in AGPRs
#define RES_BYTES  (NW * 16 * 1024)            // 65536: kt4 resident, 16 frags/wave
#define TRN_BYTES  (NW * 2 * 8 * 1024)         // 65536: 2 bufs x 8 frags per wave
#define A_STRIDE 344                           // bf16 elems; 688B rows, 16B-aligned
#define A_BYTES (16 * A_STRIDE * 2)            // 11008
#define A_OFF   (RES_BYTES + TRN_BYTES)        // 131072
#define SMEM_TOTAL (A_OFF + A_BYTES + 64 + 64) // 142208 <= 160K

__device__ __forceinline__ float fsig(float xv) {
    return __builtin_amdgcn_rcpf(1.f + __expf(-xv));
}
__device__ __forceinline__ float ftanh(float xv) {
    return fmaf(2.f, fsig(2.f * xv), -1.f);
}
__device__ __forceinline__ void mfma_a(f32x4& acc, v4i av, v4i bv) {
    asm("v_mfma_f32_16x16x32_bf16 %0, %1, %2, %0" : "+v"(acc) : "v"(av), "a"(bv));
}
__device__ __forceinline__ void mfma_v(f32x4& acc, v4i av, v4i bv) {
    asm("v_mfma_f32_16x16x32_bf16 %0, %1, %2, %0" : "+v"(acc) : "v"(av), "v"(bv));
}
// async 16B/lane global->LDS DMA; ldsptr must be wave-uniform (HW adds lane*16)
__device__ __forceinline__ void glds16(const __bf16* g, __bf16* l) {
    __builtin_amdgcn_global_load_lds(
        (const __attribute__((address_space(1))) void*)g,
        (__attribute__((address_space(3))) void*)l, 16, 0, 0);
}
// flat fragment id: wave w owns i = g*4 + jt (g=gate 0..3, jt=col-tile 0..3)
__device__ __forceinline__ int fid(int kt, int w, int i) {
    return (kt * 4 + w) * 16 + i;
}

// ---------------- prep: swizzle W into MFMA B-fragment order (bf16) ----------------
// 640 fragments (kt 0..9, w 0..3, i 0..15), 1KB each: total 640KB in d_ws.
// frag(kt,w,i): lane L holds W[n][k], n = (i>>2)*256 + w*64 + (i&3)*16 + (L&15),
//               k = kt*32 + (L>>4)*8 + j, j=0..7.
__global__ void prep_w(const float* __restrict__ W_ih, const float* __restrict__ W_hh,
                       __bf16* __restrict__ wsz) {
    int gtid = blockIdx.x * 256 + threadIdx.x;   // 0..40959
    int lane = gtid & 63;
    int frag = gtid >> 6;                        // 0..639
    int kt = frag >> 6;
    int w  = (frag >> 4) & 3;
    int nt = frag & 15;
    int g = nt >> 2, jt = nt & 3;
    int n  = g * 256 + w * 64 + jt * 16 + (lane & 15);
    int k0 = kt * 32 + ((lane >> 4) << 3);
    v8bf v;
#pragma unroll
    for (int j = 0; j < 8; ++j) {
        int k = k0 + j;
        float f = (k < 64) ? W_ih[n * 64 + k] : W_hh[n * 256 + (k - 64)];
        v[j] = (__bf16)f;
    }
    *reinterpret_cast<v8bf*>(wsz + (size_t)frag * 512 + lane * 8) = v;
}

// ---------------- fused persistent scan ----------------
__global__ __launch_bounds__(THREADS, 1) __attribute__((amdgpu_waves_per_eu(1)))
void tlstm_scan(
    const float* __restrict__ x, const __bf16* __restrict__ wsz,
    const float* __restrict__ b_ih, const float* __restrict__ b_hh,
    const float* __restrict__ Wt, const float* __restrict__ bt,
    const float* __restrict__ Wf, const float* __restrict__ bfp,
    float* __restrict__ out) {
    extern __shared__ char smem[];
    __bf16* resW  = reinterpret_cast<__bf16*>(smem);                   // 64KB kt4
    __bf16* trn   = reinterpret_cast<__bf16*>(smem + RES_BYTES);       // 64KB transit
    __bf16* A     = reinterpret_cast<__bf16*>(smem + A_OFF);           // 16 x 344 bf16
    float* td_lds = reinterpret_cast<float*>(smem + A_OFF + A_BYTES);  // 16 f32
    float* out_acc = reinterpret_cast<float*>(smem + A_OFF + A_BYTES + 64);

    const int tid  = threadIdx.x;
    const int lane = tid & 63;
    const int w    = tid >> 6;     // 0..3
    const int l15  = lane & 15;
    const int lhi  = lane >> 4;
    const int b0   = blockIdx.x * MBLK;

    const __bf16* wsz_l = wsz + (size_t)lane * 8;   // lane offset folded in

    // ---- one-time: W kt 0..3 -> wreg (pinned to AGPRs by mfma_a's "a" use)
    v4i wreg[WREG_KT * 16];
#pragma unroll
    for (int kt = 0; kt < WREG_KT; ++kt)
#pragma unroll
        for (int i = 0; i < 16; ++i)
            wreg[kt * 16 + i] = *reinterpret_cast<const v4i*>(
                wsz_l + (size_t)fid(kt, w, i) * 512);

    // ---- one-time: W kt4 -> this wave's resident LDS slab (16 frags)
#pragma unroll
    for (int i = 0; i < 16; ++i)
        *reinterpret_cast<v4i*>(resW + ((size_t)(w * 16 + i) * 64 + lane) * 8) =
            *reinterpret_cast<const v4i*>(wsz_l + (size_t)fid(WREG_KT, w, i) * 512);

    // zero A (h region must start at 0)
    for (int i = tid; i < 16 * A_STRIDE; i += THREADS) A[i] = (__bf16)0.f;
    if (tid < 16) out_acc[tid] = 0.f;

    // per-lane constants: 4 column slots jt=0..3 at col = w*64 + jt*16 + l15
    float bias[4][4], wt_r[4], bt_r[4], wf_r[4];
#pragma unroll
    for (int jt = 0; jt < 4; ++jt) {
        int col = w * 64 + jt * 16 + l15;
#pragma unroll
        for (int g = 0; g < 4; ++g) bias[g][jt] = b_ih[g * 256 + col] + b_hh[g * 256 + col];
        wt_r[jt] = Wt[col];
        bt_r[jt] = bt[col];
        wf_r[jt] = Wf[col];
    }

    float cst[4][4];   // fp32 cell state: [jt][reg]
#pragma unroll
    for (int jt = 0; jt < 4; ++jt)
#pragma unroll
        for (int r = 0; r < 4; ++r) cst[jt][r] = 0.f;
    float outp[4] = {0.f, 0.f, 0.f, 0.f};

    // x staging: 256 threads cover 16 rows x 16 chunks of 4 features
    const int xr = tid >> 4;   // row 0..15
    const int xc = tid & 15;   // feature quad 0..15
    const float* xbase = x + (size_t)(b0 + xr) * T_SZ * IN_SZ;

    // prefetch x(t=0)
    float px[4], ptd = 0.f;
    {
        const float* p = xbase;
#pragma unroll
        for (int j = 0; j < 4; ++j) px[j] = p[1 + xc * 4 + j];
        if (xc == 0) ptd = p[0];
    }

    __syncthreads();           // resW + A zero visible

    for (int t = 0; t < T_SZ; ++t) {
        // ---- stage x_t (from prefetch regs) + td into LDS
        {
            v4bf vv;
#pragma unroll
            for (int j = 0; j < 4; ++j) vv[j] = (__bf16)px[j];
            *reinterpret_cast<v4bf*>(A + xr * A_STRIDE + xc * 4) = vv;
            if (xc == 0) td_lds[xr] = ptd;
        }
        __syncthreads();   // barrier A: x_t + h(t-1) ready in LDS

        // ---- A fragments + tdv: ALL shared-LDS reads of this step happen here
        v4i a[NKT];
#pragma unroll
        for (int kt = 0; kt < NKT; ++kt)
            a[kt] = *reinterpret_cast<const v4i*>(A + l15 * A_STRIDE + kt * 32 + lhi * 8);
        float tdv[4];
#pragma unroll
        for (int r = 0; r < 4; ++r) tdv[r] = td_lds[lhi * 4 + r];

        __syncthreads();   // barrier B: below is barrier-free until next barrier A

        // ---- DMA issue: batches 0,1 of the streamed tier (16 loads in flight)
#pragma unroll
        for (int s = 0; s < 2; ++s)
#pragma unroll
            for (int j = 0; j < 8; ++j)
                glds16(wsz_l + (size_t)fid(5, w, s * 8 + j) * 512,
                       trn + (size_t)((w * 2 + s) * 8 + j) * 512);

        // ---- x(t+1) prefetch (younger than batches 0,1 in the vmcnt queue)
        {
            int tn = (t + 1 < T_SZ) ? t + 1 : t;
            const float* p = xbase + (size_t)tn * IN_SZ;
#pragma unroll
            for (int j = 0; j < 4; ++j) px[j] = p[1 + xc * 4 + j];
            if (xc == 0) ptd = p[0];
        }

        f32x4 acc[16];
#pragma unroll
        for (int i = 0; i < 16; ++i) acc[i] = (f32x4){0.f, 0.f, 0.f, 0.f};

        // ---- kt 0..3 from AGPRs (64 MFMA; covers DMA latency)
#pragma unroll
        for (int kt = 0; kt < WREG_KT; ++kt)
#pragma unroll
            for (int i = 0; i < 16; ++i)
                mfma_a(acc[i], a[kt], wreg[kt * 16 + i]);

        // ---- kt4 from resident LDS (16 MFMA)
#pragma unroll
        for (int i = 0; i < 16; ++i) {
            v4i b = *reinterpret_cast<const v4i*>(
                resW + ((size_t)(w * 16 + i) * 64 + lane) * 8);
            mfma_v(acc[i], a[WREG_KT], b);
        }

        // ---- kt 5..9 streamed: 10 batches x 8 frags through transit dbuf
#pragma unroll
        for (int s = 0; s < 10; ++s) {
            const int kt = 5 + (s >> 1);
            const int i0 = (s & 1) * 8;
            const int p  = s & 1;
            // wait for batch s: allow (younger outstanding) loads
            if (s < 2)       __builtin_amdgcn_s_waitcnt(0xF7A);  // vmcnt(10)
            else if (s == 9) __builtin_amdgcn_s_waitcnt(0xF70);  // vmcnt(0)
            else             __builtin_amdgcn_s_waitcnt(0xF78);  // vmcnt(8)
            v4i bfr[8];
#pragma unroll
            for (int j = 0; j < 8; ++j)
                bfr[j] = *reinterpret_cast<const v4i*>(
                    trn + (size_t)((w * 2 + p) * 8 + j) * 512 + lane * 8);
#pragma unroll
            for (int j = 0; j < 8; ++j)
                mfma_v(acc[i0 + j], a[kt], bfr[j]);
            if (s < 8) {   // refill this buffer with batch s+2 (same parity/i0)
                const int kn = 5 + ((s + 2) >> 1);
#pragma unroll
                for (int j = 0; j < 8; ++j)
                    glds16(wsz_l + (size_t)fid(kn, w, i0 + j) * 512,
                           trn + (size_t)((w * 2 + p) * 8 + j) * 512);
            }
        }

        // ---- lane-local LSTM epilogue (all 4 gates for this lane's 4 columns)
        const bool last = (t == T_SZ - 1);
#pragma unroll
        for (int jt = 0; jt < 4; ++jt) {
#pragma unroll
            for (int r = 0; r < 4; ++r) {
                float pi = acc[0 * 4 + jt][r] + bias[0][jt];
                float pf = acc[1 * 4 + jt][r] + bias[1][jt];
                float pg = acc[2 * 4 + jt][r] + bias[2][jt];
                float po = acc[3 * 4 + jt][r] + bias[3][jt];
                float d  = fsig(fmaf(tdv[r], wt_r[jt], bt_r[jt]));
                float c  = cst[jt][r] * d;                    // c *= decay
                c = fsig(pf) * c + fsig(pi) * ftanh(pg);      // c = f*c + i*g
                cst[jt][r] = c;
                float h = fsig(po) * ftanh(c);                // h = o*tanh(c)
                int row = lhi * 4 + r;
                int col = w * 64 + jt * 16 + l15;
                A[row * A_STRIDE + 64 + col] = (__bf16)h;     // h -> A layout for next step
                if (last) outp[r] = fmaf(h, wf_r[jt], outp[r]);
            }
        }
    }

    // ---- output: out[b] = h_T . Wf + bf
#pragma unroll
    for (int r = 0; r < 4; ++r) atomicAdd(&out_acc[lhi * 4 + r], outp[r]);
    __syncthreads();
    if (tid < 16) out[b0 + tid] = out_acc[tid] + bfp[0];
}

extern "C" void kernel_launch(void* const* d_in, const int* in_sizes, int n_in,
                              void* d_out, int out_size, void* d_ws, size_t ws_size,
                              hipStream_t stream) {
    const float* x    = (const float*)d_in[0];
    const float* W_ih = (const float*)d_in[1];
    const float* W_hh = (const float*)d_in[2];
    const float* b_ih = (const float*)d_in[3];
    const float* b_hh = (const float*)d_in[4];
    const float* Wt   = (const float*)d_in[5];
    const float* bt   = (const float*)d_in[6];
    const float* Wf   = (const float*)d_in[7];
    const float* bfp  = (const float*)d_in[8];
    float* out  = (float*)d_out;
    __bf16* wsz = (__bf16*)d_ws;   // 640KB of swizzled bf16 W

    (void)in_sizes; (void)n_in; (void)out_size; (void)ws_size;

    hipFuncSetAttribute(reinterpret_cast<const void*>(tlstm_scan),
                        hipFuncAttributeMaxDynamicSharedMemorySize, SMEM_TOTAL);

    prep_w<<<dim3(160), dim3(256), 0, stream>>>(W_ih, W_hh, wsz);
    tlstm_scan<<<dim3(NBLOCKS), dim3(THREADS), SMEM_TOTAL, stream>>>(
        x, wsz, b_ih, b_hh, Wt, bt, Wf, bfp, out);
}

// Round 8
// 2373.666 us; speedup vs baseline: 1.0015x; 1.0015x over previous
//
#include <hip/hip_runtime.h>
#include <hip/hip_bf16.h>

// TimeLSTM: B=2048, T=256, IN=65 (1 time-delta + 64 features), H=256, gates=1024.
//
// Round 8: max TLP, intrinsics only.
// Evidence r1/r5/r6: per-step time insensitive to stream size AND mechanism =>
// latency-bound with no TLP. r7 (2 waves/SIMD + asm MFMA) corrupted results:
// inline-asm MFMA isn't seen by LLVM's hazard recognizer (no wait-state
// insertion) and the 241/256-reg budget left no scheduling slack. This round:
// NO inline asm (intrinsic MFMA => compiler-managed hazards), 16 waves
// (1024 thr) = 4 waves/SIMD so co-resident waves hide each other's stalls.
//
// Per-wave register plan sized for the 128-reg cap (4 waves/SIMD):
//   acc[4] (16, AGPR) + stream lookahead bs[3][2] (24) + on-demand a (8)
//   + state/addr (~60) ~= 111 < 128 -> no spills.
// W tiers (wave w owns cols w*16+l15; frag(kt,g) = (kt*4+(w>>2))*16+g*4+(w&3)):
//   kt 0..1 -> LDS-resident (16 waves x 8 frags x 1KB = 128KB, loaded once)
//   kt 2..9 -> streamed from L2 each step (32KB/wave, 512KB/CU/step),
//              2-frag groups, 3-deep lookahead (6 loads in flight/wave,
//              24/SIMD across 4 waves => BW-bound, not latency-bound).
// Step structure (r2 placement, race-audited):
//   stage x_t -> barA -> GEMM with on-demand A reads + tdv read -> barB ->
//   epilogue (h->A) -> loop. A reads in [barA,barB); h/x writes in [barB,barA).
// C/D layout (m89): col=lane&15, row=(lane>>4)*4+reg. All 4 gates of a column
// in one lane (acc[g]) -> lane-local epilogue.

typedef __bf16 v8bf __attribute__((ext_vector_type(8)));
typedef float f32x4 __attribute__((ext_vector_type(4)));
typedef int   v4i  __attribute__((ext_vector_type(4)));

#define B_SZ 2048
#define T_SZ 256
#define IN_SZ 65
#define NKT 10          // 320 / 32 k-steps
#define MBLK 16
#define NBLOCKS (B_SZ / MBLK)   // 128
#define THREADS 1024
#define NW 16

#define LDSW_KT 2                              // kt 0..1 LDS-resident
#define SKT0 LDSW_KT                           // first streamed kt = 2
#define LDSW_BYTES (NW * LDSW_KT * 4 * 1024)   // 131072
#define A_STRIDE 344                           // bf16; 688B rows, 16B-aligned
#define A_BYTES (16 * A_STRIDE * 2)            // 11008
#define SMEM_TOTAL (LDSW_BYTES + A_BYTES + 64 + 64)   // 142208 <= 160K

__device__ __forceinline__ float fsig(float xv) {
    return __builtin_amdgcn_rcpf(1.f + __expf(-xv));
}
__device__ __forceinline__ float ftanh(float xv) {
    return fmaf(2.f, fsig(2.f * xv), -1.f);
}
// fragment id for wave w (wq=w>>2, jt=w&3), gate g
__device__ __forceinline__ int fid(int kt, int w, int g) {
    return (kt * 4 + (w >> 2)) * 16 + g * 4 + (w & 3);
}

// ---------------- prep: swizzle W into MFMA B-fragment order (bf16) ----------------
// 640 fragments (kt 0..9, wq 0..3, nt 0..15), 1KB each: total 640KB in d_ws.
// frag(kt,wq,nt): lane L holds W[n][k], n=(nt>>2)*256+wq*64+(nt&3)*16+(L&15),
//                 k = kt*32 + (L>>4)*8 + j, j=0..7.
__global__ void prep_w(const float* __restrict__ W_ih, const float* __restrict__ W_hh,
                       __bf16* __restrict__ wsz) {
    int gtid = blockIdx.x * 256 + threadIdx.x;   // 0..40959
    int lane = gtid & 63;
    int frag = gtid >> 6;                        // 0..639
    int kt = frag >> 6;
    int wq = (frag >> 4) & 3;
    int nt = frag & 15;
    int g = nt >> 2, jt = nt & 3;
    int n  = g * 256 + wq * 64 + jt * 16 + (lane & 15);
    int k0 = kt * 32 + ((lane >> 4) << 3);
    v8bf v;
#pragma unroll
    for (int j = 0; j < 8; ++j) {
        int k = k0 + j;
        float f = (k < 64) ? W_ih[n * 64 + k] : W_hh[n * 256 + (k - 64)];
        v[j] = (__bf16)f;
    }
    *reinterpret_cast<v8bf*>(wsz + (size_t)frag * 512 + lane * 8) = v;
}

// ---------------- fused persistent scan ----------------
__global__ __launch_bounds__(THREADS, 1) __attribute__((amdgpu_waves_per_eu(4, 4)))
void tlstm_scan(
    const float* __restrict__ x, const __bf16* __restrict__ wsz,
    const float* __restrict__ b_ih, const float* __restrict__ b_hh,
    const float* __restrict__ Wt, const float* __restrict__ bt,
    const float* __restrict__ Wf, const float* __restrict__ bfp,
    float* __restrict__ out) {
    extern __shared__ char smem[];
    __bf16* ldsW  = reinterpret_cast<__bf16*>(smem);                       // 128KB kt0..1
    __bf16* A     = reinterpret_cast<__bf16*>(smem + LDSW_BYTES);          // 16 x 344 bf16
    float* td_lds = reinterpret_cast<float*>(smem + LDSW_BYTES + A_BYTES); // 16 f32
    float* out_acc = reinterpret_cast<float*>(smem + LDSW_BYTES + A_BYTES + 64);

    const int tid  = threadIdx.x;
    const int lane = tid & 63;
    const int w    = tid >> 6;     // 0..15
    const int l15  = lane & 15;
    const int lhi  = lane >> 4;
    const int b0   = blockIdx.x * MBLK;

    const __bf16* wsz_l = wsz + (size_t)lane * 8;   // lane offset folded in

    // ---- one-time: W kt 0..1 -> this wave's LDS slab (8 frags x 1KB)
#pragma unroll
    for (int kt = 0; kt < LDSW_KT; ++kt)
#pragma unroll
        for (int g = 0; g < 4; ++g)
            *reinterpret_cast<v4i*>(
                ldsW + ((size_t)((w * LDSW_KT + kt) * 4 + g) * 64 + lane) * 8) =
                *reinterpret_cast<const v4i*>(wsz_l + (size_t)fid(kt, w, g) * 512);

    // zero A (h region must start at 0)
    for (int i = tid; i < 16 * A_STRIDE; i += THREADS) A[i] = (__bf16)0.f;
    if (tid < 16) out_acc[tid] = 0.f;

    // per-lane constants: this lane's column col = w*16 + l15
    const int col = w * 16 + l15;
    float bias[4];
#pragma unroll
    for (int g = 0; g < 4; ++g) bias[g] = b_ih[g * 256 + col] + b_hh[g * 256 + col];
    const float wt_r = Wt[col];
    const float bt_r = bt[col];
    const float wf_r = Wf[col];

    float cst[4];   // fp32 cell state per acc row r
#pragma unroll
    for (int r = 0; r < 4; ++r) cst[r] = 0.f;
    float outp[4] = {0.f, 0.f, 0.f, 0.f};

    // x staging: 1024 threads cover 16 rows x 64 features
    const int xr = tid >> 6;   // row 0..15
    const int xf = tid & 63;   // feature 0..63
    const float* xbase = x + (size_t)(b0 + xr) * T_SZ * IN_SZ;

    // prefetch x(t=0)
    float px, ptd = 0.f;
    {
        px = xbase[1 + xf];
        if (xf == 0) ptd = xbase[0];
    }

    __syncthreads();           // ldsW + A zero visible

    for (int t = 0; t < T_SZ; ++t) {
        // ---- stage x_t (from prefetch regs) + td into LDS
        A[xr * A_STRIDE + xf] = (__bf16)px;
        if (xf == 0) td_lds[xr] = ptd;
        __syncthreads();   // barrier A: x_t + h(t-1) ready in LDS

        // ---- x(t+1) prefetch (lands well before barrier B's vmcnt drain)
        {
            int tn = (t + 1 < T_SZ) ? t + 1 : t;
            const float* p = xbase + (size_t)tn * IN_SZ;
            px = p[1 + xf];
            if (xf == 0) ptd = p[0];
        }

        // ---- tdv must be read inside [barA, barB): td_lds is rewritten by
        //      faster waves at stage(t+1), which happens after their barB.
        float tdv[4];
#pragma unroll
        for (int r = 0; r < 4; ++r) tdv[r] = td_lds[lhi * 4 + r];

        const __bf16* arow = A + l15 * A_STRIDE + lhi * 8;   // a-frag base

        f32x4 acc[4];
#pragma unroll
        for (int g = 0; g < 4; ++g) acc[g] = (f32x4){0.f, 0.f, 0.f, 0.f};

        // ---- stream prologue: 3 groups of 2 frags (kt2: g01,g23; kt3: g01)
        v4i bs[3][2];
#pragma unroll
        for (int s = 0; s < 3; ++s) {
            int kt = SKT0 + (s >> 1);
            int g0 = (s & 1) * 2;
#pragma unroll
            for (int i = 0; i < 2; ++i)
                bs[s][i] = *reinterpret_cast<const v4i*>(
                    wsz_l + (size_t)fid(kt, w, g0 + i) * 512);
        }

        // ---- kt 0..1 from resident LDS (on-demand a reads)
#pragma unroll
        for (int kt = 0; kt < LDSW_KT; ++kt) {
            v4i av = *reinterpret_cast<const v4i*>(arow + kt * 32);
#pragma unroll
            for (int g = 0; g < 4; ++g) {
                v4i b = *reinterpret_cast<const v4i*>(
                    ldsW + ((size_t)((w * LDSW_KT + kt) * 4 + g) * 64 + lane) * 8);
                acc[g] = __builtin_amdgcn_mfma_f32_16x16x32_bf16(
                    (v8bf)av, (v8bf)b, acc[g], 0, 0, 0);
            }
        }

        // ---- kt 2..9 streamed: 16 groups of 2 frags, 3-deep lookahead
#pragma unroll
        for (int s = 0; s < 16; ++s) {
            const int kt = SKT0 + (s >> 1);
            const int g0 = (s & 1) * 2;
            v4i av = *reinterpret_cast<const v4i*>(arow + kt * 32);
            v4i bc[2];
#pragma unroll
            for (int i = 0; i < 2; ++i) bc[i] = bs[s % 3][i];
            if (s < 13) {   // refill consumed buffer with group s+3
                const int sn = s + 3;
                const int kn = SKT0 + (sn >> 1);
                const int gn = (sn & 1) * 2;
#pragma unroll
                for (int i = 0; i < 2; ++i)
                    bs[s % 3][i] = *reinterpret_cast<const v4i*>(
                        wsz_l + (size_t)fid(kn, w, gn + i) * 512);
            }
#pragma unroll
            for (int i = 0; i < 2; ++i)
                acc[g0 + i] = __builtin_amdgcn_mfma_f32_16x16x32_bf16(
                    (v8bf)av, (v8bf)bc[i], acc[g0 + i], 0, 0, 0);
        }

        __syncthreads();   // barrier B: all A reads done; h/x writes may begin

        // ---- lane-local LSTM epilogue (all 4 gates for this lane's column)
        const bool last = (t == T_SZ - 1);
#pragma unroll
        for (int r = 0; r < 4; ++r) {
            float pi = acc[0][r] + bias[0];
            float pf = acc[1][r] + bias[1];
            float pg = acc[2][r] + bias[2];
            float po = acc[3][r] + bias[3];
            float d  = fsig(fmaf(tdv[r], wt_r, bt_r));
            float c  = cst[r] * d;                        // c *= decay
            c = fsig(pf) * c + fsig(pi) * ftanh(pg);      // c = f*c + i*g
            cst[r] = c;
            float h = fsig(po) * ftanh(c);                // h = o*tanh(c)
            int row = lhi * 4 + r;
            A[row * A_STRIDE + 64 + col] = (__bf16)h;     // h -> A layout for next step
            if (last) outp[r] = fmaf(h, wf_r, outp[r]);
        }
    }

    // ---- output: out[b] = h_T . Wf + bf
#pragma unroll
    for (int r = 0; r < 4; ++r) atomicAdd(&out_acc[lhi * 4 + r], outp[r]);
    __syncthreads();
    if (tid < 16) out[b0 + tid] = out_acc[tid] + bfp[0];
}

extern "C" void kernel_launch(void* const* d_in, const int* in_sizes, int n_in,
                              void* d_out, int out_size, void* d_ws, size_t ws_size,
                              hipStream_t stream) {
    const float* x    = (const float*)d_in[0];
    const float* W_ih = (const float*)d_in[1];
    const float* W_hh = (const float*)d_in[2];
    const float* b_ih = (const float*)d_in[3];
    const float* b_hh = (const float*)d_in[4];
    const float* Wt   = (const float*)d_in[5];
    const float* bt   = (const float*)d_in[6];
    const float* Wf   = (const float*)d_in[7];
    const float* bfp  = (const float*)d_in[8];
    float* out  = (float*)d_out;
    __bf16* wsz = (__bf16*)d_ws;   // 640KB of swizzled bf16 W

    (void)in_sizes; (void)n_in; (void)out_size; (void)ws_size;

    hipFuncSetAttribute(reinterpret_cast<const void*>(tlstm_scan),
                        hipFuncAttributeMaxDynamicSharedMemorySize, SMEM_TOTAL);

    prep_w<<<dim3(160), dim3(256), 0, stream>>>(W_ih, W_hh, wsz);
    tlstm_scan<<<dim3(NBLOCKS), dim3(THREADS), SMEM_TOTAL, stream>>>(
        x, wsz, b_ih, b_hh, Wt, bt, Wf, bfp, out);
}